// Round 22
// baseline (99.510 us; speedup 1.0000x reference)
//
#include <hip/hip_runtime.h>
#include <hip/hip_bf16.h>
#include <stdint.h>

#define NFRM 8
#define NPTS 4096
#define NBOX 128
#define NS   32
#define TT   4
#define BB   2
#define FEATC 99
#define OUT1OFF (BB*NBOX*TT*NS*5)   /* 163840 */

/* ---- workspace layout (bytes) ---- */
#define WS_SPK    0u
#define WS_EPK    524288u
#define WS_FEATS  786432u
#define WS_SIDX   13762560u
#define WS_FLAGS  13893632u
#define WS_NCNT   14024704u
#define WS_NLST   14024736u
#define WS_VPK    14155808u
#define WS_VEK    14680096u
#define WS_VORIG  14942240u
#define WS_VCNT   15073312u
#define WS_WT     15073344u
#define WS_CCNT   15089728u   /* per-chunk valid counts: 8*16 ints */

__device__ __forceinline__ float rdl(float x, int l){
    return __int_as_float(__builtin_amdgcn_readlane(__float_as_int(x), l));
}

/* -- K1: validity + packed arrays + per-chunk counts; block128 = wT ------ */
__global__ void k_prep(const float* __restrict__ pts, const float* __restrict__ rois,
                       float4* __restrict__ spk, float2* __restrict__ epk,
                       const float* __restrict__ w00,const float* __restrict__ w01,
                       const float* __restrict__ w02,const float* __restrict__ w10,
                       const float* __restrict__ w11,const float* __restrict__ w12,
                       float* __restrict__ wt, int* __restrict__ flags,
                       int* __restrict__ gcnt, int* __restrict__ ccnt)
{
    if (blockIdx.x == 128){
        int t = threadIdx.x;
        if (t == 0) *gcnt = 0;
        for (int idx=t; idx<80;   idx+=256){ int o=idx/5,  i=idx%5;  wt[      i*16+o]=w00[idx]; }
        for (int idx=t; idx<256;  idx+=256){ int o=idx/16, i=idx%16; wt[  80+ i*16+o]=w01[idx]; }
        for (int idx=t; idx<512;  idx+=256){ int o=idx/16, i=idx%16; wt[ 336+ i*32+o]=w02[idx]; }
        for (int idx=t; idx<160;  idx+=256){ int o=idx/5,  i=idx%5;  wt[ 848+ i*32+o]=w10[idx]; }
        for (int idx=t; idx<1024; idx+=256){ int o=idx/32, i=idx%32; wt[1008+ i*32+o]=w11[idx]; }
        for (int idx=t; idx<2048; idx+=256){ int o=idx/32, i=idx%32; wt[2032+ i*64+o]=w12[idx]; }
        return;
    }
    int f = blockIdx.x >> 4;
    int chunk = blockIdx.x & 15;
    int tid = threadIdx.x, wv = tid >> 6, lane = tid & 63;
    int n = (chunk << 8) | tid;
    __shared__ float bqx[NBOX], bqy[NBOX], brv[NBOX];
    __shared__ int wcnt[4];
    if (tid < NBOX){
        const float* bp = rois + (size_t)(f*NBOX + tid)*7;
        float bx=bp[0], by=bp[1], dx=bp[3], dy=bp[4];
        float hx=__fmul_rn(dx,0.5f), hy=__fmul_rn(dy,0.5f);
        float hd=sqrtf(__fadd_rn(__fmul_rn(hx,hx),__fmul_rn(hy,hy)));
        brv[tid]=ceilf(__fdiv_rn(__fmul_rn(hd,1.1f),0.4f));
        bqx[tid]=floorf(__fdiv_rn(__fsub_rn(bx,-75.2f),0.4f));
        bqy[tid]=floorf(__fdiv_rn(__fsub_rn(by,-75.2f),0.4f));
    }
    flags[f*NPTS+n] = 0;
    __syncthreads();
    const float* pp = pts + (size_t)(f*NPTS+n)*5;
    float x=pp[0], y=pp[1], z=pp[2], it=pp[3], ts=pp[4];
    float cx=floorf(__fdiv_rn(__fsub_rn(x,-75.2f),0.4f));
    float cy=floorf(__fdiv_rn(__fsub_rn(y,-75.2f),0.4f));
    bool pred=false;
    for (int m=0;m<NBOX;m++)
        if (fabsf(bqx[m]-cx)<brv[m] && fabsf(bqy[m]-cy)<brv[m]){ pred=true; break; }
    spk[f*NPTS+n]=make_float4(x,y,z,pred?1.f:0.f);
    epk[f*NPTS+n]=make_float2(it,ts);
    uint64_t m = __ballot(pred);
    if (lane == 0) wcnt[wv] = __popcll(m);
    __syncthreads();
    if (tid == 0) ccnt[f*16+chunk] = wcnt[0]+wcnt[1]+wcnt[2]+wcnt[3];
}

/* -- K1b: parallel order-preserving compaction (1 block per 256-chunk) --- */
__global__ void k_valid(const float4* __restrict__ spk, const float2* __restrict__ epk,
                        const int* __restrict__ ccnt,
                        float4* __restrict__ vpk, float2* __restrict__ vek,
                        int* __restrict__ vorig, int* __restrict__ vcnt)
{
    int f = blockIdx.x >> 4;
    int chunk = blockIdx.x & 15;
    int tid = threadIdx.x, wv = tid >> 6, lane = tid & 63;
    __shared__ int wcnt[4];
    int base = 0;
    for (int i=0;i<chunk;i++) base += ccnt[f*16+i];
    int j = (chunk << 8) | tid;
    float4 q = spk[f*NPTS+j];
    float2 e = epk[f*NPTS+j];
    bool pred = q.w > 0.5f;
    uint64_t m = __ballot(pred);
    uint64_t below = (1ull<<lane)-1ull;
    int lp = __popcll(m & below);
    if (lane == 0) wcnt[wv] = __popcll(m);
    __syncthreads();
    int off = base;
    for (int w=0; w<wv; w++) off += wcnt[w];
    if (pred){
        int pos = off + lp;
        float sb = __fadd_rn(__fadd_rn(__fmul_rn(q.x,q.x),__fmul_rn(q.y,q.y)),__fmul_rn(q.z,q.z));
        vpk[f*NPTS+pos] = make_float4(q.x,q.y,q.z,sb);
        vek[f*NPTS+pos] = e;
        vorig[f*NPTS+pos] = j;
    }
    if (chunk == 15 && tid == 0){
        int t = base + wcnt[0]+wcnt[1]+wcnt[2]+wcnt[3];
        vcnt[f] = t;
    }
}

/* ------ K2: per-box stable top-k; 4 boxes/block (wave = box) ------------ */
__global__ __launch_bounds__(256) void k_select(
    const float4* __restrict__ spk, const float2* __restrict__ epk,
    const float4* __restrict__ vpk, const int* __restrict__ vorig,
    const int* __restrict__ vcnt,
    const float* __restrict__ rois, float* __restrict__ out,
    int* __restrict__ sidx, int* __restrict__ flags,
    int* __restrict__ gcnt, int* __restrict__ glist)
{
    int wv = threadIdx.x >> 6, lane = threadIdx.x & 63;
    int id = blockIdx.x*4 + wv;    /* 0..1023 : (f, m) */
    int f = id >> 7, m = id & 127;
    const float* bp = rois + (size_t)(f*NBOX+m)*7;
    float bx=bp[0], by=bp[1], dx=bp[3], dy=bp[4];
    float hx=__fmul_rn(dx,0.5f), hy=__fmul_rn(dy,0.5f);
    float hd=sqrtf(__fadd_rn(__fmul_rn(hx,hx),__fmul_rn(hy,hy)));
    float rr=__fmul_rn(hd,1.1f);

    __shared__ int lt[4][32], lf[4][32];
    int* ltw = lt[wv];
    int* lfw = lf[wv];
    const float4* fsp = spk + f*NPTS;
    const float4* fvp = vpk + f*NPTS;
    const int*    fvo = vorig + f*NPTS;
    int vc = vcnt[f];
    uint64_t below = (1ull<<lane)-1ull;

    /* phase A: masked candidates from valid list, 2-deep pipelined */
    int cT=0;
    for (int v0=0; v0<vc; v0+=128){
        int viA = v0 + lane;
        int viB = v0 + 64 + lane;
        int vicA = min(viA, vc-1);
        int vicB = min(viB, vc-1);
        float4 qA = fvp[vicA];
        float4 qB = fvp[vicB];
        {
            float ddx=__fsub_rn(bx,qA.x), ddy=__fsub_rn(by,qA.y);
            float dis=sqrtf(__fadd_rn(__fmul_rn(ddx,ddx),__fmul_rn(ddy,ddy)));
            bool pm = (viA < vc) && (dis <= rr);
            uint64_t mT=__ballot(pm);
            if (pm){ int pos=cT+__popcll(mT&below); if (pos<32) ltw[pos]=fvo[vicA]; }
            cT += __popcll(mT);
            if (cT>=32) break;
        }
        if (v0 + 64 < vc){
            float ddx=__fsub_rn(bx,qB.x), ddy=__fsub_rn(by,qB.y);
            float dis=sqrtf(__fadd_rn(__fmul_rn(ddx,ddx),__fmul_rn(ddy,ddy)));
            bool pm = (viB < vc) && (dis <= rr);
            uint64_t mT=__ballot(pm);
            if (pm){ int pos=cT+__popcll(mT&below); if (pos<32) ltw[pos]=fvo[vicB]; }
            cT += __popcll(mT);
            if (cT>=32) break;
        }
    }
    /* phase B: fillers = first 32 original indices failing the mask */
    int cF=0;
    for (int j0=0; j0<NPTS; j0+=64){
        int j=j0+lane;
        float4 q = fsp[j];
        float ddx=__fsub_rn(bx,q.x), ddy=__fsub_rn(by,q.y);
        float dis=sqrtf(__fadd_rn(__fmul_rn(ddx,ddx),__fmul_rn(ddy,ddy)));
        bool fl = !((dis <= rr) && (q.w > 0.5f));
        uint64_t mF=__ballot(fl);
        if (fl){ int pos=cF+__popcll(mF&below); if (pos<32) lfw[pos]=j; }
        cF += __popcll(mF);
        if (cF>=32) break;
    }
    cT = min(cT,32);
    if (lane < 32){
        int s = lane;
        bool masked = s < cT;
        int idx = masked ? ltw[s] : lfw[s-cT];
        float mk = masked ? 1.f : 0.f;
        sidx[(f*NBOX+m)*NS+s]=idx;
        int b = f >> 2, t = f & 3;
        size_t row = (((size_t)(b*NBOX+m))*TT + t)*NS + s;
        float4 q = fsp[idx]; float2 e = epk[f*NPTS+idx];
        float* o0 = out + row*5;
        o0[0]=q.x*mk; o0[1]=q.y*mk; o0[2]=q.z*mk; o0[3]=e.x*mk; o0[4]=e.y*mk;
        /* fused dedupe-append to global needlist */
        int old = atomicExch(&flags[f*NPTS+idx], 1);
        bool fresh = (old == 0);
        uint64_t mm = __ballot(fresh);
        if (fresh){
            int ldr = __ffsll((unsigned long long)mm) - 1;
            int base = 0;
            if (lane == ldr) base = atomicAdd(gcnt, __popcll(mm));
            base = __shfl(base, ldr);
            glist[base + __popcll(mm & below)] = (f<<12) | idx;
        }
    }
}

/* -- K4: scan + channel-major MLPs; MLP0 rdl-bcast, MLP1 LDS f4-bcast ---- */
__global__ __launch_bounds__(256) void k_mlp(
    const float4* __restrict__ spk, const float2* __restrict__ epk,
    const float4* __restrict__ vpk, const float2* __restrict__ vek,
    const int* __restrict__ vcnt,
    const int* __restrict__ gcntp, const int* __restrict__ glist,
    float* __restrict__ feats, const float* __restrict__ wt,
    const float* __restrict__ b00,const float* __restrict__ b01,
    const float* __restrict__ b02,const float* __restrict__ b10,
    const float* __restrict__ b11,const float* __restrict__ b12)
{
    int gcnt = *gcntp;
    if ((int)blockIdx.x * 4 >= gcnt) return;
    int tid = threadIdx.x;
    int wv = tid >> 6, lane = tid & 63;
    __shared__ int lists[4][48];
    __shared__ float h1buf[4][8][36];
    __shared__ float h2buf[4][8][36];
    int* l1 = lists[wv];
    int* l2 = lists[wv]+16;
    float (*h1b)[36] = h1buf[wv];
    float (*h2b)[36] = h2buf[wv];

    /* ---- per-lane weight rows, loaded COALESCED from transposed copy ---- */
    float wr00[5], wr01[16], wr02[16], wr10[5], wr11[32], wr12[32];
    float br00=0.f, br01=0.f, br02=0.f, br10=0.f, br11=0.f, br12=0.f;
    #pragma unroll
    for (int i=0;i<5;i++){ wr00[i]=0.f; wr10[i]=0.f; }
    #pragma unroll
    for (int i=0;i<16;i++){ wr01[i]=0.f; wr02[i]=0.f; }
    #pragma unroll
    for (int i=0;i<32;i++){ wr11[i]=0.f; wr12[i]=0.f; }
    if (lane < 16){
        #pragma unroll
        for (int i=0;i<5;i++)  wr00[i]=wt[i*16+lane];
        br00=b00[lane];
        #pragma unroll
        for (int i=0;i<16;i++) wr01[i]=wt[80+i*16+lane];
        br01=b01[lane];
    }
    if (lane < 32){
        #pragma unroll
        for (int i=0;i<16;i++) wr02[i]=wt[336+i*32+lane];
        br02=b02[lane];
        #pragma unroll
        for (int i=0;i<5;i++)  wr10[i]=wt[848+i*32+lane];
        br10=b10[lane];
        #pragma unroll
        for (int i=0;i<32;i++) wr11[i]=wt[1008+i*32+lane];
        br11=b11[lane];
    }
    #pragma unroll
    for (int i=0;i<32;i++) wr12[i]=wt[2032+i*64+lane];
    br12=b12[lane];

    const float RR1 = (float)(0.8*0.8);
    const float RR2 = (float)(1.6*1.6);
    uint64_t below = (1ull<<lane)-1ull;

    for (int li = blockIdx.x*4 + wv; li < gcnt; li += 8192){
        int pe = glist[li];
        int f = pe >> 12, n = pe & 4095;
        const float4* fsp = spk + f*NPTS;
        const float2* fep = epk + f*NPTS;
        const float4* fvp = vpk + f*NPTS;
        const float2* fve = vek + f*NPTS;
        int vc = vcnt[f];
        float4 me = fsp[n];
        float sa = __fadd_rn(__fadd_rn(__fmul_rn(me.x,me.x),__fmul_rn(me.y,me.y)),__fmul_rn(me.z,me.z));

        /* ---- neighbor scan over valid list ---- */
        int cnt1=0, cnt2=0;
        for (int v0=0; v0<vc; v0+=64){
            int vi = v0 + lane;
            int vic = min(vi, vc-1);
            float4 q = fvp[vic];
            float dot = __fadd_rn(__fadd_rn(__fmul_rn(me.x,q.x),__fmul_rn(me.y,q.y)),__fmul_rn(me.z,q.z));
            float d2 = fmaxf(__fsub_rn(__fadd_rn(sa,q.w),__fmul_rn(2.0f,dot)), 0.f);
            bool inb = (vi < vc);
            bool p1 = inb && (d2 < RR1);
            bool p2 = inb && (d2 < RR2);
            uint64_t m1 = __ballot(p1), m2 = __ballot(p2);
            if (p1){ int pos = cnt1 + __popcll(m1 & below); if (pos < 16) l1[pos] = vi; }
            if (p2){ int pos = cnt2 + __popcll(m2 & below); if (pos < 32) l2[pos] = vi; }
            cnt1 += __popcll(m1); cnt2 += __popcll(m2);
            if (cnt1 >= 16 && cnt2 >= 32) break;
        }
        cnt1 = min(cnt1,16); cnt2 = min(cnt2,32);

        float* fo = feats + (size_t)(f*NPTS+n)*FEATC;
        float4 q0 = fsp[0]; float2 e0 = fep[0];

        /* ---- MLP0: 16 nbrs, 5->16->16->32, batches of 8, rdl bcast ---- */
        {
            float pmax = 0.f;
            #pragma unroll 1
            for (int kb=0; kb<16; kb+=8){
                float4 qb[8]; float2 eb[8];
                #pragma unroll
                for (int j=0;j<8;j++){
                    int kk = kb+j;
                    int vi = (cnt1>0) ? ((kk<cnt1)? l1[kk] : l1[0]) : -1;
                    if (vi >= 0){ qb[j]=fvp[vi]; eb[j]=fve[vi]; }
                    else        { qb[j]=q0;      eb[j]=e0; }
                }
                float h1[8];
                #pragma unroll
                for (int j=0;j<8;j++){
                    float a1 = br00;
                    a1 += __fsub_rn(qb[j].x,me.x)*wr00[0];
                    a1 += __fsub_rn(qb[j].y,me.y)*wr00[1];
                    a1 += __fsub_rn(qb[j].z,me.z)*wr00[2];
                    a1 += eb[j].x*wr00[3];
                    a1 += eb[j].y*wr00[4];
                    h1[j] = fmaxf(a1,0.f);
                }
                float a2[8] = {br01,br01,br01,br01,br01,br01,br01,br01};
                #pragma unroll
                for (int c=0;c<16;c++){
                    float w = wr01[c];
                    #pragma unroll
                    for (int j=0;j<8;j++) a2[j] += rdl(h1[j],c)*w;
                }
                float h2[8];
                #pragma unroll
                for (int j=0;j<8;j++) h2[j] = fmaxf(a2[j],0.f);
                float a3[8] = {br02,br02,br02,br02,br02,br02,br02,br02};
                #pragma unroll
                for (int c=0;c<16;c++){
                    float w = wr02[c];
                    #pragma unroll
                    for (int j=0;j<8;j++) a3[j] += rdl(h2[j],c)*w;
                }
                #pragma unroll
                for (int j=0;j<8;j++) pmax = fmaxf(pmax, fmaxf(a3[j],0.f));
            }
            if (lane < 3){
                float mv = (lane==0)? me.x : ((lane==1)? me.y : me.z);
                fo[lane] = mv;
            }
            if (lane < 32) fo[3+lane] = pmax;
        }

        /* ---- MLP1: 32 nbrs, 5->32->32->64, batches of 8, LDS h-bcast ---- */
        {
            float pmax = 0.f;
            #pragma unroll 1
            for (int kb=0; kb<32; kb+=8){
                float4 qb[8]; float2 eb[8];
                #pragma unroll
                for (int j=0;j<8;j++){
                    int kk = kb+j;
                    int vi = (cnt2>0) ? ((kk<cnt2)? l2[kk] : l2[0]) : -1;
                    if (vi >= 0){ qb[j]=fvp[vi]; eb[j]=fve[vi]; }
                    else        { qb[j]=q0;      eb[j]=e0; }
                }
                #pragma unroll
                for (int j=0;j<8;j++){
                    float a1 = br10;
                    a1 += __fsub_rn(qb[j].x,me.x)*wr10[0];
                    a1 += __fsub_rn(qb[j].y,me.y)*wr10[1];
                    a1 += __fsub_rn(qb[j].z,me.z)*wr10[2];
                    a1 += eb[j].x*wr10[3];
                    a1 += eb[j].y*wr10[4];
                    float h = fmaxf(a1,0.f);
                    if (lane < 32) h1b[j][lane] = h;
                }
                float a2[8] = {br11,br11,br11,br11,br11,br11,br11,br11};
                #pragma unroll
                for (int c4=0;c4<8;c4++){
                    float4 hv[8];
                    #pragma unroll
                    for (int j=0;j<8;j++) hv[j] = *(const float4*)&h1b[j][c4*4];
                    #pragma unroll
                    for (int cc=0;cc<4;cc++){
                        float w = wr11[c4*4+cc];
                        #pragma unroll
                        for (int j=0;j<8;j++){
                            float h = (cc==0)?hv[j].x:(cc==1)?hv[j].y:(cc==2)?hv[j].z:hv[j].w;
                            a2[j] += h*w;
                        }
                    }
                }
                #pragma unroll
                for (int j=0;j<8;j++){
                    float h = fmaxf(a2[j],0.f);
                    if (lane < 32) h2b[j][lane] = h;
                }
                float a3[8] = {br12,br12,br12,br12,br12,br12,br12,br12};
                #pragma unroll
                for (int c4=0;c4<8;c4++){
                    float4 hv[8];
                    #pragma unroll
                    for (int j=0;j<8;j++) hv[j] = *(const float4*)&h2b[j][c4*4];
                    #pragma unroll
                    for (int cc=0;cc<4;cc++){
                        float w = wr12[c4*4+cc];
                        #pragma unroll
                        for (int j=0;j<8;j++){
                            float h = (cc==0)?hv[j].x:(cc==1)?hv[j].y:(cc==2)?hv[j].z:hv[j].w;
                            a3[j] += h*w;
                        }
                    }
                }
                #pragma unroll
                for (int j=0;j<8;j++) pmax = fmaxf(pmax, fmaxf(a3[j],0.f));
            }
            fo[35+lane] = pmax;
        }
    }
}

/* ---------------- K5: gather feats rows -> out1 ------------------------- */
__global__ void k_gather(const float* __restrict__ feats, const int* __restrict__ sidx,
                         float* __restrict__ out)
{
    int id = blockIdx.x;           /* 0..1023 : (f, m) */
    int f = id >> 7, m = id & 127;
    int tid = threadIdx.x;
    int s = tid >> 3, j = tid & 7;
    int idx = sidx[(f*NBOX+m)*NS+s];
    int b = f >> 2, t = f & 3;
    size_t row = (((size_t)(b*NBOX+m))*TT + t)*NS + s;
    const float* fi = feats + (size_t)(f*NPTS+idx)*FEATC;
    float* o1 = out + OUT1OFF + row*FEATC;
    for (int c=j; c<FEATC; c+=8) o1[c]=fi[c];
}

extern "C" void kernel_launch(void* const* d_in, const int* in_sizes, int n_in,
                              void* d_out, int out_size, void* d_ws, size_t ws_size,
                              hipStream_t stream)
{
    const float* pts  = (const float*)d_in[0];
    const float* rois = (const float*)d_in[1];
    const float* w00=(const float*)d_in[2],  *b00=(const float*)d_in[3];
    const float* w01=(const float*)d_in[4],  *b01=(const float*)d_in[5];
    const float* w02=(const float*)d_in[6],  *b02=(const float*)d_in[7];
    const float* w10=(const float*)d_in[8],  *b10=(const float*)d_in[9];
    const float* w11=(const float*)d_in[10], *b11=(const float*)d_in[11];
    const float* w12=(const float*)d_in[12], *b12=(const float*)d_in[13];
    float* out = (float*)d_out;

    char* ws = (char*)d_ws;
    float4* spk   = (float4*)(ws + WS_SPK);
    float2* epk   = (float2*)(ws + WS_EPK);
    float*  feats = (float*) (ws + WS_FEATS);
    int*    sidx  = (int*)   (ws + WS_SIDX);
    int*    flags = (int*)   (ws + WS_FLAGS);
    int*    gcnt  = (int*)   (ws + WS_NCNT);
    int*    glist = (int*)   (ws + WS_NLST);
    float4* vpk   = (float4*)(ws + WS_VPK);
    float2* vek   = (float2*)(ws + WS_VEK);
    int*    vorig = (int*)   (ws + WS_VORIG);
    int*    vcnt  = (int*)   (ws + WS_VCNT);
    float*  wtr   = (float*) (ws + WS_WT);
    int*    ccnt  = (int*)   (ws + WS_CCNT);

    hipLaunchKernelGGL(k_prep,   dim3(NFRM*16+1), dim3(256), 0, stream,
                       pts, rois, spk, epk, w00,w01,w02,w10,w11,w12, wtr, flags, gcnt, ccnt);
    hipLaunchKernelGGL(k_valid,  dim3(NFRM*16), dim3(256), 0, stream,
                       spk, epk, ccnt, vpk, vek, vorig, vcnt);
    hipLaunchKernelGGL(k_select, dim3(NFRM*NBOX/4), dim3(256), 0, stream,
                       spk, epk, vpk, vorig, vcnt, rois, out, sidx, flags, gcnt, glist);
    hipLaunchKernelGGL(k_mlp,    dim3(2048), dim3(256), 0, stream,
                       spk, epk, vpk, vek, vcnt, gcnt, glist, feats, wtr,
                       b00,b01,b02,b10,b11,b12);
    hipLaunchKernelGGL(k_gather, dim3(NFRM*NBOX), dim3(256), 0, stream,
                       feats, sidx, out);
}

// Round 24
// 95.642 us; speedup vs baseline: 1.0404x; 1.0404x over previous
//
#include <hip/hip_runtime.h>
#include <hip/hip_bf16.h>
#include <stdint.h>

#define NFRM 8
#define NPTS 4096
#define NBOX 128
#define NS   32
#define TT   4
#define BB   2
#define FEATC 99
#define OUT1OFF (BB*NBOX*TT*NS*5)   /* 163840 */

/* ---- workspace layout (bytes) ---- */
#define WS_SPK    0u
#define WS_EPK    524288u
#define WS_FEATS  786432u
#define WS_SIDX   13762560u
#define WS_FLAGS  13893632u
#define WS_NCNT   14024704u
#define WS_NLST   14024736u
#define WS_VPK    14155808u
#define WS_VEK    14680096u
#define WS_VORIG  14942240u
#define WS_VCNT   15073312u
#define WS_WT     15073344u
#define WS_CCNT   15089728u   /* per-chunk valid counts: 8*16 ints */

/* -- K1: validity + packed arrays + per-chunk counts; block128 = wT ------ */
__global__ void k_prep(const float* __restrict__ pts, const float* __restrict__ rois,
                       float4* __restrict__ spk, float2* __restrict__ epk,
                       const float* __restrict__ w00,const float* __restrict__ w01,
                       const float* __restrict__ w02,const float* __restrict__ w10,
                       const float* __restrict__ w11,const float* __restrict__ w12,
                       float* __restrict__ wt, int* __restrict__ flags,
                       int* __restrict__ gcnt, int* __restrict__ ccnt)
{
    if (blockIdx.x == 128){
        int t = threadIdx.x;
        if (t == 0) *gcnt = 0;
        for (int idx=t; idx<80;   idx+=256){ int o=idx/5,  i=idx%5;  wt[      i*16+o]=w00[idx]; }
        for (int idx=t; idx<256;  idx+=256){ int o=idx/16, i=idx%16; wt[  80+ i*16+o]=w01[idx]; }
        for (int idx=t; idx<512;  idx+=256){ int o=idx/16, i=idx%16; wt[ 336+ i*32+o]=w02[idx]; }
        for (int idx=t; idx<160;  idx+=256){ int o=idx/5,  i=idx%5;  wt[ 848+ i*32+o]=w10[idx]; }
        for (int idx=t; idx<1024; idx+=256){ int o=idx/32, i=idx%32; wt[1008+ i*32+o]=w11[idx]; }
        for (int idx=t; idx<2048; idx+=256){ int o=idx/32, i=idx%32; wt[2032+ i*64+o]=w12[idx]; }
        return;
    }
    int f = blockIdx.x >> 4;
    int chunk = blockIdx.x & 15;
    int tid = threadIdx.x, wv = tid >> 6, lane = tid & 63;
    int n = (chunk << 8) | tid;
    __shared__ float bqx[NBOX], bqy[NBOX], brv[NBOX];
    __shared__ int wcnt[4];
    if (tid < NBOX){
        const float* bp = rois + (size_t)(f*NBOX + tid)*7;
        float bx=bp[0], by=bp[1], dx=bp[3], dy=bp[4];
        float hx=__fmul_rn(dx,0.5f), hy=__fmul_rn(dy,0.5f);
        float hd=sqrtf(__fadd_rn(__fmul_rn(hx,hx),__fmul_rn(hy,hy)));
        brv[tid]=ceilf(__fdiv_rn(__fmul_rn(hd,1.1f),0.4f));
        bqx[tid]=floorf(__fdiv_rn(__fsub_rn(bx,-75.2f),0.4f));
        bqy[tid]=floorf(__fdiv_rn(__fsub_rn(by,-75.2f),0.4f));
    }
    flags[f*NPTS+n] = 0;
    __syncthreads();
    const float* pp = pts + (size_t)(f*NPTS+n)*5;
    float x=pp[0], y=pp[1], z=pp[2], it=pp[3], ts=pp[4];
    float cx=floorf(__fdiv_rn(__fsub_rn(x,-75.2f),0.4f));
    float cy=floorf(__fdiv_rn(__fsub_rn(y,-75.2f),0.4f));
    bool pred=false;
    for (int m=0;m<NBOX;m++)
        if (fabsf(bqx[m]-cx)<brv[m] && fabsf(bqy[m]-cy)<brv[m]){ pred=true; break; }
    spk[f*NPTS+n]=make_float4(x,y,z,pred?1.f:0.f);
    epk[f*NPTS+n]=make_float2(it,ts);
    uint64_t m = __ballot(pred);
    if (lane == 0) wcnt[wv] = __popcll(m);
    __syncthreads();
    if (tid == 0) ccnt[f*16+chunk] = wcnt[0]+wcnt[1]+wcnt[2]+wcnt[3];
}

/* -- K1b: parallel order-preserving compaction (1 block per 256-chunk) --- */
__global__ void k_valid(const float4* __restrict__ spk, const float2* __restrict__ epk,
                        const int* __restrict__ ccnt,
                        float4* __restrict__ vpk, float2* __restrict__ vek,
                        int* __restrict__ vorig, int* __restrict__ vcnt)
{
    int f = blockIdx.x >> 4;
    int chunk = blockIdx.x & 15;
    int tid = threadIdx.x, wv = tid >> 6, lane = tid & 63;
    __shared__ int wcnt[4];
    int base = 0;
    for (int i=0;i<chunk;i++) base += ccnt[f*16+i];
    int j = (chunk << 8) | tid;
    float4 q = spk[f*NPTS+j];
    float2 e = epk[f*NPTS+j];
    bool pred = q.w > 0.5f;
    uint64_t m = __ballot(pred);
    uint64_t below = (1ull<<lane)-1ull;
    int lp = __popcll(m & below);
    if (lane == 0) wcnt[wv] = __popcll(m);
    __syncthreads();
    int off = base;
    for (int w=0; w<wv; w++) off += wcnt[w];
    if (pred){
        int pos = off + lp;
        float sb = __fadd_rn(__fadd_rn(__fmul_rn(q.x,q.x),__fmul_rn(q.y,q.y)),__fmul_rn(q.z,q.z));
        vpk[f*NPTS+pos] = make_float4(q.x,q.y,q.z,sb);
        vek[f*NPTS+pos] = e;
        vorig[f*NPTS+pos] = j;
    }
    if (chunk == 15 && tid == 0){
        int t = base + wcnt[0]+wcnt[1]+wcnt[2]+wcnt[3];
        vcnt[f] = t;
    }
}

/* ------ K2: per-box stable top-k; 4 boxes/block (wave = box) ------------ */
__global__ __launch_bounds__(256) void k_select(
    const float4* __restrict__ spk, const float2* __restrict__ epk,
    const float4* __restrict__ vpk, const int* __restrict__ vorig,
    const int* __restrict__ vcnt,
    const float* __restrict__ rois, float* __restrict__ out,
    int* __restrict__ sidx, int* __restrict__ flags,
    int* __restrict__ gcnt, int* __restrict__ glist)
{
    int wv = threadIdx.x >> 6, lane = threadIdx.x & 63;
    int id = blockIdx.x*4 + wv;    /* 0..1023 : (f, m) */
    int f = id >> 7, m = id & 127;
    const float* bp = rois + (size_t)(f*NBOX+m)*7;
    float bx=bp[0], by=bp[1], dx=bp[3], dy=bp[4];
    float hx=__fmul_rn(dx,0.5f), hy=__fmul_rn(dy,0.5f);
    float hd=sqrtf(__fadd_rn(__fmul_rn(hx,hx),__fmul_rn(hy,hy)));
    float rr=__fmul_rn(hd,1.1f);

    __shared__ int lt[4][32], lf[4][32];
    int* ltw = lt[wv];
    int* lfw = lf[wv];
    const float4* fsp = spk + f*NPTS;
    const float4* fvp = vpk + f*NPTS;
    const int*    fvo = vorig + f*NPTS;
    int vc = vcnt[f];
    uint64_t below = (1ull<<lane)-1ull;

    /* phase A: masked candidates from valid list, 2-deep pipelined */
    int cT=0;
    for (int v0=0; v0<vc; v0+=128){
        int viA = v0 + lane;
        int viB = v0 + 64 + lane;
        int vicA = min(viA, vc-1);
        int vicB = min(viB, vc-1);
        float4 qA = fvp[vicA];
        float4 qB = fvp[vicB];
        {
            float ddx=__fsub_rn(bx,qA.x), ddy=__fsub_rn(by,qA.y);
            float dis=sqrtf(__fadd_rn(__fmul_rn(ddx,ddx),__fmul_rn(ddy,ddy)));
            bool pm = (viA < vc) && (dis <= rr);
            uint64_t mT=__ballot(pm);
            if (pm){ int pos=cT+__popcll(mT&below); if (pos<32) ltw[pos]=fvo[vicA]; }
            cT += __popcll(mT);
            if (cT>=32) break;
        }
        if (v0 + 64 < vc){
            float ddx=__fsub_rn(bx,qB.x), ddy=__fsub_rn(by,qB.y);
            float dis=sqrtf(__fadd_rn(__fmul_rn(ddx,ddx),__fmul_rn(ddy,ddy)));
            bool pm = (viB < vc) && (dis <= rr);
            uint64_t mT=__ballot(pm);
            if (pm){ int pos=cT+__popcll(mT&below); if (pos<32) ltw[pos]=fvo[vicB]; }
            cT += __popcll(mT);
            if (cT>=32) break;
        }
    }
    /* phase B: fillers = first 32 original indices failing the mask */
    int cF=0;
    for (int j0=0; j0<NPTS; j0+=64){
        int j=j0+lane;
        float4 q = fsp[j];
        float ddx=__fsub_rn(bx,q.x), ddy=__fsub_rn(by,q.y);
        float dis=sqrtf(__fadd_rn(__fmul_rn(ddx,ddx),__fmul_rn(ddy,ddy)));
        bool fl = !((dis <= rr) && (q.w > 0.5f));
        uint64_t mF=__ballot(fl);
        if (fl){ int pos=cF+__popcll(mF&below); if (pos<32) lfw[pos]=j; }
        cF += __popcll(mF);
        if (cF>=32) break;
    }
    cT = min(cT,32);
    if (lane < 32){
        int s = lane;
        bool masked = s < cT;
        int idx = masked ? ltw[s] : lfw[s-cT];
        float mk = masked ? 1.f : 0.f;
        sidx[(f*NBOX+m)*NS+s]=idx;
        int b = f >> 2, t = f & 3;
        size_t row = (((size_t)(b*NBOX+m))*TT + t)*NS + s;
        float4 q = fsp[idx]; float2 e = epk[f*NPTS+idx];
        float* o0 = out + row*5;
        o0[0]=q.x*mk; o0[1]=q.y*mk; o0[2]=q.z*mk; o0[3]=e.x*mk; o0[4]=e.y*mk;
        /* fused dedupe-append to global needlist */
        int old = atomicExch(&flags[f*NPTS+idx], 1);
        bool fresh = (old == 0);
        uint64_t mm = __ballot(fresh);
        if (fresh){
            int ldr = __ffsll((unsigned long long)mm) - 1;
            int base = 0;
            if (lane == ldr) base = atomicAdd(gcnt, __popcll(mm));
            base = __shfl(base, ldr);
            glist[base + __popcll(mm & below)] = (f<<12) | idx;
        }
    }
}

/* -- K4: scan + channel-major MLPs; LDS float4 h-bcast; ILP-8 batches ---- */
__global__ __launch_bounds__(256) void k_mlp(
    const float4* __restrict__ spk, const float2* __restrict__ epk,
    const float4* __restrict__ vpk, const float2* __restrict__ vek,
    const int* __restrict__ vcnt,
    const int* __restrict__ gcntp, const int* __restrict__ glist,
    float* __restrict__ feats, const float* __restrict__ wt,
    const float* __restrict__ b00,const float* __restrict__ b01,
    const float* __restrict__ b02,const float* __restrict__ b10,
    const float* __restrict__ b11,const float* __restrict__ b12)
{
    int gcnt = *gcntp;
    if ((int)blockIdx.x * 4 >= gcnt) return;
    int tid = threadIdx.x;
    int wv = tid >> 6, lane = tid & 63;
    __shared__ int lists[4][48];
    __shared__ float h1buf[4][8][36];
    __shared__ float h2buf[4][8][36];
    int* l1 = lists[wv];
    int* l2 = lists[wv]+16;
    float (*h1b)[36] = h1buf[wv];
    float (*h2b)[36] = h2buf[wv];

    /* ---- per-lane weight rows, loaded COALESCED from transposed copy ---- */
    float wr00[5], wr01[16], wr02[16], wr10[5], wr11[32], wr12[32];
    float br00=0.f, br01=0.f, br02=0.f, br10=0.f, br11=0.f, br12=0.f;
    #pragma unroll
    for (int i=0;i<5;i++){ wr00[i]=0.f; wr10[i]=0.f; }
    #pragma unroll
    for (int i=0;i<16;i++){ wr01[i]=0.f; wr02[i]=0.f; }
    #pragma unroll
    for (int i=0;i<32;i++){ wr11[i]=0.f; wr12[i]=0.f; }
    if (lane < 16){
        #pragma unroll
        for (int i=0;i<5;i++)  wr00[i]=wt[i*16+lane];
        br00=b00[lane];
        #pragma unroll
        for (int i=0;i<16;i++) wr01[i]=wt[80+i*16+lane];
        br01=b01[lane];
    }
    if (lane < 32){
        #pragma unroll
        for (int i=0;i<16;i++) wr02[i]=wt[336+i*32+lane];
        br02=b02[lane];
        #pragma unroll
        for (int i=0;i<5;i++)  wr10[i]=wt[848+i*32+lane];
        br10=b10[lane];
        #pragma unroll
        for (int i=0;i<32;i++) wr11[i]=wt[1008+i*32+lane];
        br11=b11[lane];
    }
    #pragma unroll
    for (int i=0;i<32;i++) wr12[i]=wt[2032+i*64+lane];
    br12=b12[lane];

    const float RR1 = (float)(0.8*0.8);
    const float RR2 = (float)(1.6*1.6);
    uint64_t below = (1ull<<lane)-1ull;

    for (int li = blockIdx.x*4 + wv; li < gcnt; li += 8192){
        int pe = glist[li];
        int f = pe >> 12, n = pe & 4095;
        const float4* fsp = spk + f*NPTS;
        const float2* fep = epk + f*NPTS;
        const float4* fvp = vpk + f*NPTS;
        const float2* fve = vek + f*NPTS;
        int vc = vcnt[f];
        float4 me = fsp[n];
        float sa = __fadd_rn(__fadd_rn(__fmul_rn(me.x,me.x),__fmul_rn(me.y,me.y)),__fmul_rn(me.z,me.z));

        /* ---- neighbor scan over valid list ---- */
        int cnt1=0, cnt2=0;
        for (int v0=0; v0<vc; v0+=64){
            int vi = v0 + lane;
            int vic = min(vi, vc-1);
            float4 q = fvp[vic];
            float dot = __fadd_rn(__fadd_rn(__fmul_rn(me.x,q.x),__fmul_rn(me.y,q.y)),__fmul_rn(me.z,q.z));
            float d2 = fmaxf(__fsub_rn(__fadd_rn(sa,q.w),__fmul_rn(2.0f,dot)), 0.f);
            bool inb = (vi < vc);
            bool p1 = inb && (d2 < RR1);
            bool p2 = inb && (d2 < RR2);
            uint64_t m1 = __ballot(p1), m2 = __ballot(p2);
            if (p1){ int pos = cnt1 + __popcll(m1 & below); if (pos < 16) l1[pos] = vi; }
            if (p2){ int pos = cnt2 + __popcll(m2 & below); if (pos < 32) l2[pos] = vi; }
            cnt1 += __popcll(m1); cnt2 += __popcll(m2);
            if (cnt1 >= 16 && cnt2 >= 32) break;
        }
        cnt1 = min(cnt1,16); cnt2 = min(cnt2,32);

        float* fo = feats + (size_t)(f*NPTS+n)*FEATC;
        float4 q0 = fsp[0]; float2 e0 = fep[0];

        /* ---- MLP0: 16 nbrs, 5->16->16->32, batches of 8, LDS h-bcast ---- */
        {
            float pmax = 0.f;
            #pragma unroll 1
            for (int kb=0; kb<16; kb+=8){
                float4 qb[8]; float2 eb[8];
                #pragma unroll
                for (int j=0;j<8;j++){
                    int kk = kb+j;
                    int vi = (cnt1>0) ? ((kk<cnt1)? l1[kk] : l1[0]) : -1;
                    if (vi >= 0){ qb[j]=fvp[vi]; eb[j]=fve[vi]; }
                    else        { qb[j]=q0;      eb[j]=e0; }
                }
                #pragma unroll
                for (int j=0;j<8;j++){
                    float a1 = br00;
                    a1 += __fsub_rn(qb[j].x,me.x)*wr00[0];
                    a1 += __fsub_rn(qb[j].y,me.y)*wr00[1];
                    a1 += __fsub_rn(qb[j].z,me.z)*wr00[2];
                    a1 += eb[j].x*wr00[3];
                    a1 += eb[j].y*wr00[4];
                    float h = fmaxf(a1,0.f);
                    if (lane < 16) h1b[j][lane] = h;
                }
                float a2[8] = {br01,br01,br01,br01,br01,br01,br01,br01};
                #pragma unroll
                for (int c4=0;c4<4;c4++){
                    float4 hv[8];
                    #pragma unroll
                    for (int j=0;j<8;j++) hv[j] = *(const float4*)&h1b[j][c4*4];
                    #pragma unroll
                    for (int cc=0;cc<4;cc++){
                        float w = wr01[c4*4+cc];
                        #pragma unroll
                        for (int j=0;j<8;j++){
                            float h = (cc==0)?hv[j].x:(cc==1)?hv[j].y:(cc==2)?hv[j].z:hv[j].w;
                            a2[j] += h*w;
                        }
                    }
                }
                #pragma unroll
                for (int j=0;j<8;j++){
                    float h = fmaxf(a2[j],0.f);
                    if (lane < 16) h2b[j][lane] = h;
                }
                float a3[8] = {br02,br02,br02,br02,br02,br02,br02,br02};
                #pragma unroll
                for (int c4=0;c4<4;c4++){
                    float4 hv[8];
                    #pragma unroll
                    for (int j=0;j<8;j++) hv[j] = *(const float4*)&h2b[j][c4*4];
                    #pragma unroll
                    for (int cc=0;cc<4;cc++){
                        float w = wr02[c4*4+cc];
                        #pragma unroll
                        for (int j=0;j<8;j++){
                            float h = (cc==0)?hv[j].x:(cc==1)?hv[j].y:(cc==2)?hv[j].z:hv[j].w;
                            a3[j] += h*w;
                        }
                    }
                }
                #pragma unroll
                for (int j=0;j<8;j++) pmax = fmaxf(pmax, fmaxf(a3[j],0.f));
            }
            if (lane < 3){
                float mv = (lane==0)? me.x : ((lane==1)? me.y : me.z);
                fo[lane] = mv;
            }
            if (lane < 32) fo[3+lane] = pmax;
        }

        /* ---- MLP1: 32 nbrs, 5->32->32->64, batches of 8, LDS h-bcast ---- */
        {
            float pmax = 0.f;
            #pragma unroll 1
            for (int kb=0; kb<32; kb+=8){
                float4 qb[8]; float2 eb[8];
                #pragma unroll
                for (int j=0;j<8;j++){
                    int kk = kb+j;
                    int vi = (cnt2>0) ? ((kk<cnt2)? l2[kk] : l2[0]) : -1;
                    if (vi >= 0){ qb[j]=fvp[vi]; eb[j]=fve[vi]; }
                    else        { qb[j]=q0;      eb[j]=e0; }
                }
                #pragma unroll
                for (int j=0;j<8;j++){
                    float a1 = br10;
                    a1 += __fsub_rn(qb[j].x,me.x)*wr10[0];
                    a1 += __fsub_rn(qb[j].y,me.y)*wr10[1];
                    a1 += __fsub_rn(qb[j].z,me.z)*wr10[2];
                    a1 += eb[j].x*wr10[3];
                    a1 += eb[j].y*wr10[4];
                    float h = fmaxf(a1,0.f);
                    if (lane < 32) h1b[j][lane] = h;
                }
                float a2[8] = {br11,br11,br11,br11,br11,br11,br11,br11};
                #pragma unroll
                for (int c4=0;c4<8;c4++){
                    float4 hv[8];
                    #pragma unroll
                    for (int j=0;j<8;j++) hv[j] = *(const float4*)&h1b[j][c4*4];
                    #pragma unroll
                    for (int cc=0;cc<4;cc++){
                        float w = wr11[c4*4+cc];
                        #pragma unroll
                        for (int j=0;j<8;j++){
                            float h = (cc==0)?hv[j].x:(cc==1)?hv[j].y:(cc==2)?hv[j].z:hv[j].w;
                            a2[j] += h*w;
                        }
                    }
                }
                #pragma unroll
                for (int j=0;j<8;j++){
                    float h = fmaxf(a2[j],0.f);
                    if (lane < 32) h2b[j][lane] = h;
                }
                float a3[8] = {br12,br12,br12,br12,br12,br12,br12,br12};
                #pragma unroll
                for (int c4=0;c4<8;c4++){
                    float4 hv[8];
                    #pragma unroll
                    for (int j=0;j<8;j++) hv[j] = *(const float4*)&h2b[j][c4*4];
                    #pragma unroll
                    for (int cc=0;cc<4;cc++){
                        float w = wr12[c4*4+cc];
                        #pragma unroll
                        for (int j=0;j<8;j++){
                            float h = (cc==0)?hv[j].x:(cc==1)?hv[j].y:(cc==2)?hv[j].z:hv[j].w;
                            a3[j] += h*w;
                        }
                    }
                }
                #pragma unroll
                for (int j=0;j<8;j++) pmax = fmaxf(pmax, fmaxf(a3[j],0.f));
            }
            fo[35+lane] = pmax;
        }
    }
}

/* ---------------- K5: gather feats rows -> out1 ------------------------- */
__global__ void k_gather(const float* __restrict__ feats, const int* __restrict__ sidx,
                         float* __restrict__ out)
{
    int id = blockIdx.x;           /* 0..1023 : (f, m) */
    int f = id >> 7, m = id & 127;
    int tid = threadIdx.x;
    int s = tid >> 3, j = tid & 7;
    int idx = sidx[(f*NBOX+m)*NS+s];
    int b = f >> 2, t = f & 3;
    size_t row = (((size_t)(b*NBOX+m))*TT + t)*NS + s;
    const float* fi = feats + (size_t)(f*NPTS+idx)*FEATC;
    float* o1 = out + OUT1OFF + row*FEATC;
    for (int c=j; c<FEATC; c+=8) o1[c]=fi[c];
}

extern "C" void kernel_launch(void* const* d_in, const int* in_sizes, int n_in,
                              void* d_out, int out_size, void* d_ws, size_t ws_size,
                              hipStream_t stream)
{
    const float* pts  = (const float*)d_in[0];
    const float* rois = (const float*)d_in[1];
    const float* w00=(const float*)d_in[2],  *b00=(const float*)d_in[3];
    const float* w01=(const float*)d_in[4],  *b01=(const float*)d_in[5];
    const float* w02=(const float*)d_in[6],  *b02=(const float*)d_in[7];
    const float* w10=(const float*)d_in[8],  *b10=(const float*)d_in[9];
    const float* w11=(const float*)d_in[10], *b11=(const float*)d_in[11];
    const float* w12=(const float*)d_in[12], *b12=(const float*)d_in[13];
    float* out = (float*)d_out;

    char* ws = (char*)d_ws;
    float4* spk   = (float4*)(ws + WS_SPK);
    float2* epk   = (float2*)(ws + WS_EPK);
    float*  feats = (float*) (ws + WS_FEATS);
    int*    sidx  = (int*)   (ws + WS_SIDX);
    int*    flags = (int*)   (ws + WS_FLAGS);
    int*    gcnt  = (int*)   (ws + WS_NCNT);
    int*    glist = (int*)   (ws + WS_NLST);
    float4* vpk   = (float4*)(ws + WS_VPK);
    float2* vek   = (float2*)(ws + WS_VEK);
    int*    vorig = (int*)   (ws + WS_VORIG);
    int*    vcnt  = (int*)   (ws + WS_VCNT);
    float*  wtr   = (float*) (ws + WS_WT);
    int*    ccnt  = (int*)   (ws + WS_CCNT);

    hipLaunchKernelGGL(k_prep,   dim3(NFRM*16+1), dim3(256), 0, stream,
                       pts, rois, spk, epk, w00,w01,w02,w10,w11,w12, wtr, flags, gcnt, ccnt);
    hipLaunchKernelGGL(k_valid,  dim3(NFRM*16), dim3(256), 0, stream,
                       spk, epk, ccnt, vpk, vek, vorig, vcnt);
    hipLaunchKernelGGL(k_select, dim3(NFRM*NBOX/4), dim3(256), 0, stream,
                       spk, epk, vpk, vorig, vcnt, rois, out, sidx, flags, gcnt, glist);
    hipLaunchKernelGGL(k_mlp,    dim3(2048), dim3(256), 0, stream,
                       spk, epk, vpk, vek, vcnt, gcnt, glist, feats, wtr,
                       b00,b01,b02,b10,b11,b12);
    hipLaunchKernelGGL(k_gather, dim3(NFRM*NBOX), dim3(256), 0, stream,
                       feats, sidx, out);
}